// Round 5
// baseline (93.476 us; speedup 1.0000x reference)
//
#include <hip/hip_runtime.h>
#include <stdint.h>
#include <stddef.h>

#define BATCH 65536
#define OUTF  1024
#define INF   128

typedef float f32x4 __attribute__((ext_vector_type(4)));
typedef __bf16 bf16x8 __attribute__((ext_vector_type(8)));

// RNE float->bf16, packed pair: lo halfword = a, hi halfword = b
__device__ inline uint32_t pack_bf16_rne(float a, float b) {
    uint32_t ua = __builtin_bit_cast(uint32_t, a);
    uint32_t ub = __builtin_bit_cast(uint32_t, b);
    ua += 0x7fffu + ((ua >> 16) & 1u);
    ub += 0x7fffu + ((ub >> 16) & 1u);
    return (ua >> 16) | (ub & 0xffff0000u);
}

// Prep: one wave per row. Reads fp32 row (128 elems), writes bf16 row
// (64 u32, coalesced 256B) and the row sum-of-squares.
// rows [0, BATCH) -> x, rows [BATCH, BATCH+OUTF) -> w.
__global__ __launch_bounds__(256) void prep_kernel(
        const float* __restrict__ x, const float* __restrict__ w,
        float* __restrict__ sumsq, uint32_t* __restrict__ xb,
        uint32_t* __restrict__ wb) {
    int gtid = blockIdx.x * 256 + threadIdx.x;
    int row  = gtid >> 6;
    int lane = threadIdx.x & 63;
    if (row >= BATCH + OUTF) return;
    const float* src;
    uint32_t* dst;
    if (row < BATCH) {
        src = x + (size_t)row * INF;
        dst = xb + (size_t)row * 64;
    } else {
        src = w + (size_t)(row - BATCH) * INF;
        dst = wb + (size_t)(row - BATCH) * 64;
    }
    float2 v = *(const float2*)(src + lane * 2);
    dst[lane] = pack_bf16_rne(v.x, v.y);
    float s = v.x * v.x + v.y * v.y;
    #pragma unroll
    for (int off = 32; off; off >>= 1) s += __shfl_down(s, off);
    if (lane == 0) sumsq[row] = s;
}

#define TPAD 132  // LDS row stride (floats); 2-way bank aliasing only (free)

// 128x128 output tile per block, 4 waves (2x2), mfma 16x16x32 bf16.
// Epilogue: 4 chunks of 32 rows through double-buffered LDS (34.8 KB total)
// -> 4 blocks/CU so store drains overlap other blocks' compute.
__global__ __launch_bounds__(256, 4) void gemm_epi_kernel(
        const __bf16* __restrict__ xb, const __bf16* __restrict__ wb,
        const float* __restrict__ x2, const float* __restrict__ w2,
        float* __restrict__ out) {
    // bijective XCD-chunked swizzle: nwg = 4096 (divisible by 8).
    // Per XCD: nt sweeps fast -> 32KB x-panel L2-resident across 8 n-tiles.
    int bid = blockIdx.x;
    int swz = (bid & 7) * (4096 / 8) + (bid >> 3);
    int mt = swz >> 3;          // 512 m-tiles
    int nt = swz & 7;           // 8 n-tiles
    int m0 = mt * 128, n0 = nt * 128;

    int tid  = threadIdx.x;
    int wid  = tid >> 6;
    int lane = tid & 63;
    int wr = wid >> 1, wc = wid & 1;    // 2x2 wave grid, 64x64 per wave
    int row_base = m0 + wr * 64;
    int col_base = n0 + wc * 64;

    __shared__ float sx2[128];
    __shared__ float sw2[128];
    __shared__ float tile2[2][32 * TPAD];
    if (tid < 128) {
        sx2[tid] = x2[m0 + tid];
        sw2[tid] = w2[n0 + tid];
    }
    __syncthreads();

    int l16 = lane & 15;   // row/col within fragment
    int lq  = lane >> 4;   // k-quarter selector

    f32x4 acc[4][4];
    #pragma unroll
    for (int i = 0; i < 4; ++i)
        #pragma unroll
        for (int j = 0; j < 4; ++j)
            acc[i][j] = f32x4{0.f, 0.f, 0.f, 0.f};

    #pragma unroll
    for (int ks = 0; ks < 4; ++ks) {
        int kbase = ks * 32 + lq * 8;
        bf16x8 a[4], b[4];
        #pragma unroll
        for (int im = 0; im < 4; ++im)
            a[im] = *(const bf16x8*)(xb + (size_t)(row_base + im * 16 + l16) * INF + kbase);
        #pragma unroll
        for (int in = 0; in < 4; ++in)
            b[in] = *(const bf16x8*)(wb + (size_t)(col_base + in * 16 + l16) * INF + kbase);
        #pragma unroll
        for (int im = 0; im < 4; ++im)
            #pragma unroll
            for (int in = 0; in < 4; ++in)
                acc[im][in] = __builtin_amdgcn_mfma_f32_16x16x32_bf16(
                    a[im], b[in], acc[im][in], 0, 0, 0);
    }

    // Epilogue in 4 chunks of 32 rows, double-buffered.
    // C/D layout (verified m89/m91): col = lane&15, row = (lane>>4)*4 + reg
    // chunk c covers tile rows [32c, 32c+32): owned by waves wr == c>>1,
    // acc index im in {(c&1)*2, (c&1)*2+1}.
    int srow = tid >> 3;          // 0..31  (store row within chunk)
    int scg  = tid & 7;           // 16B col group base
    #pragma unroll
    for (int c = 0; c < 4; ++c) {
        float* buf = tile2[c & 1];
        if (wr == (c >> 1)) {
            #pragma unroll
            for (int imh = 0; imh < 2; ++imh) {
                int im = (c & 1) * 2 + imh;
                #pragma unroll
                for (int in = 0; in < 4; ++in) {
                    #pragma unroll
                    for (int r = 0; r < 4; ++r) {
                        int row  = wr * 64 + im * 16 + lq * 4 + r;  // tile row
                        int rloc = row - c * 32;                     // 0..31
                        int col  = wc * 64 + in * 16 + l16;
                        float d2 = sx2[row] + sw2[col] - 2.0f * acc[im][in][r];
                        buf[rloc * TPAD + col] =
                            -0.5f * __builtin_amdgcn_sqrtf(fmaxf(d2, 0.0f));
                    }
                }
            }
        }
        __syncthreads();
        // all 256 threads store chunk c: 32 rows x 512B, f32x4 NT stores
        size_t gbase = (size_t)(m0 + c * 32 + srow) * OUTF + n0;
        #pragma unroll
        for (int j = 0; j < 4; ++j) {
            int col4 = scg + j * 8;
            f32x4 v = *(const f32x4*)&buf[srow * TPAD + col4 * 4];
            __builtin_nontemporal_store(v, (f32x4*)&out[gbase + col4 * 4]);
        }
        // next chunk writes the other buffer; the barrier at the top of the
        // next iteration orders LDS reuse two chunks later.
    }
}

extern "C" void kernel_launch(void* const* d_in, const int* in_sizes, int n_in,
                              void* d_out, int out_size, void* d_ws, size_t ws_size,
                              hipStream_t stream) {
    const float* x = (const float*)d_in[0];
    const float* w = (const float*)d_in[1];
    float* out = (float*)d_out;

    // ws layout: [0, 66560*4) f32 sumsq (x2 then w2);
    // xb (bf16 x, 16 MiB) at byte 266240 (256-aligned); wb after it.
    char* ws = (char*)d_ws;
    float* sumsq = (float*)ws;
    float* x2 = sumsq;
    float* w2 = sumsq + BATCH;
    uint32_t* xb_u32 = (uint32_t*)(ws + 266240);
    uint32_t* wb_u32 = (uint32_t*)(ws + 266240 + (size_t)BATCH * INF * 2);
    const __bf16* xb = (const __bf16*)xb_u32;
    const __bf16* wb = (const __bf16*)wb_u32;

    prep_kernel<<<dim3((BATCH + OUTF) / 4), dim3(256), 0, stream>>>(
        x, w, sumsq, xb_u32, wb_u32);
    gemm_epi_kernel<<<dim3(4096), dim3(256), 0, stream>>>(xb, wb, x2, w2, out);
}